// Round 9
// baseline (295.129 us; speedup 1.0000x reference)
//
#include <hip/hip_runtime.h>

#define BATCH      4096
#define OBS_COLS   2304
#define OTH_OFF    2048
#define EMB        256
#define OUTC       512

// ws layout: qk (4096x256 f32) | qb (4096x4 f32) | packed pW slices (34 x 8KB)
#define QK_BYTES   (4096u * 256u * 4u)
#define QB_BYTES   (4096u * 4u * 4u)

typedef __bf16 bf16x8 __attribute__((ext_vector_type(8)));
typedef __bf16 bf16x4 __attribute__((ext_vector_type(4)));
typedef float  f32x16 __attribute__((ext_vector_type(16)));

// Slice bases (units of 512 bf16x8 = one 16x256 K-step slice) within wp
#define S_PW1  0
#define S_PW2  2
#define S_PW3  18
#define N_SLICE 34

// Swizzled element index into a [rows][256] bf16 LDS tile.
__device__ __forceinline__ int shx(int row, int col) {
    return (row << 8) + ((((col >> 3) ^ (row & 31)) << 3) | (col & 7));
}

// ---------------------------------------------------------------------------
// k_oth: 128 WGs x 512 thr (identical to R6/R8).
// ---------------------------------------------------------------------------
__global__ __launch_bounds__(512, 2) void k_oth(
    const float* __restrict__ obs,
    const float* __restrict__ oW1, const float* __restrict__ ob1,
    const float* __restrict__ oW2, const float* __restrict__ ob2,
    const float* __restrict__ Wq,  const float* __restrict__ bq,
    const float* __restrict__ Wk,  const float* __restrict__ bk,
    const float* __restrict__ pW1, const float* __restrict__ pW2,
    const float* __restrict__ pW3,
    float* __restrict__ out, float* __restrict__ qkg,
    float* __restrict__ qbg, __bf16* __restrict__ wp)
{
    __shared__ __align__(16) __bf16 s_a[32 * 256];   // 16 KB
    __shared__ __align__(16) __bf16 s_h[32 * 256];   // 16 KB
    __shared__ __align__(16) __bf16 s_q[32 * 256];   // 16 KB
    __shared__ float s_qb[32 * 4];

    const int t  = threadIdx.x;
    const int b0 = blockIdx.x * 32;
    const int wv = t >> 6, lane = t & 63;
    const int lm = lane & 31, lh = lane >> 5;
    const int ct = wv;                 // col tile 0..7

    // ---- pack pW slices for k_obj (WGs 0..33) ----
    if (blockIdx.x < N_SLICE) {
        const int s = blockIdx.x;
        int kt; const float* W; int isW1 = 0;
        if      (s < S_PW2) { kt = s;         W = pW1; isW1 = 1; }
        else if (s < S_PW3) { kt = s - S_PW2; W = pW2; }
        else                { kt = s - S_PW3; W = pW3; }
        const int kbase = kt * 16 + lh * 8;
        const int n     = (t >> 6) * 32 + lm;
        bf16x8 v;
        #pragma unroll
        for (int j = 0; j < 8; ++j) {
            const int k = kbase + j;
            const float f = (isW1 && k >= 31) ? 0.0f : W[k * 256 + n];
            v[j] = (__bf16)f;
        }
        ((bf16x8*)wp)[(size_t)s * 512 + t] = v;
    }

    // ---- stage 32 rows x 256 cols (fp32 -> bf16, swizzled) ----
    #pragma unroll
    for (int i = 0; i < 2; ++i) {
        const int c = i * 512 + t;
        const int row = c >> 5, seg = c & 31;
        const float* src = obs + (size_t)(b0 + row) * OBS_COLS + OTH_OFF + seg * 8;
        const float4 v0 = ((const float4*)src)[0];
        const float4 v1 = ((const float4*)src)[1];
        bf16x8 o;
        o[0]=(__bf16)v0.x; o[1]=(__bf16)v0.y; o[2]=(__bf16)v0.z; o[3]=(__bf16)v0.w;
        o[4]=(__bf16)v1.x; o[5]=(__bf16)v1.y; o[6]=(__bf16)v1.z; o[7]=(__bf16)v1.w;
        *(bf16x8*)&s_a[shx(row, seg * 8)] = o;
    }
    if (t < 128) s_qb[t] = 0.0f;
    __syncthreads();

    f32x16 acc;
    f32x16 vzero;
    #pragma unroll
    for (int i = 0; i < 16; ++i) vzero[i] = 0.0f;

    // ---- L1: h = relu(A @ oW1 + ob1); B direct from fp32, depth-1 rot ----
    {
        const float* Wl = oW1 + (size_t)(lh * 8) * 256 + ct * 32 + lm;
        acc = vzero;
        float f[8];
        #pragma unroll
        for (int j = 0; j < 8; ++j) f[j] = Wl[j * 256];
        #pragma unroll 4
        for (int kt = 0; kt < 16; ++kt) {
            float fn[8];
            const int kn = (kt + 1) & 15;
            #pragma unroll
            for (int j = 0; j < 8; ++j) fn[j] = Wl[(kn * 16 + j) * 256];
            bf16x8 b;
            #pragma unroll
            for (int j = 0; j < 8; ++j) b[j] = (__bf16)f[j];
            const bf16x8 a = *(const bf16x8*)&s_a[shx(lm, kt * 16 + lh * 8)];
            acc = __builtin_amdgcn_mfma_f32_32x32x16_bf16(b, a, acc, 0, 0, 0);
            #pragma unroll
            for (int j = 0; j < 8; ++j) f[j] = fn[j];
        }
        const float* bias = &ob1[ct * 32 + 4 * lh];
        #pragma unroll
        for (int g = 0; g < 4; ++g) {
            bf16x4 v;
            #pragma unroll
            for (int q = 0; q < 4; ++q)
                v[q] = (__bf16)fmaxf(acc[g * 4 + q] + bias[8 * g + q], 0.0f);
            *(bf16x4*)&s_h[(lm << 8) + ((((ct << 2) + g) ^ lm) << 3) + 4 * lh] = v;
        }
    }
    __syncthreads();

    // ---- L2: e = s_h @ oW2 + ob2 -> out (fp32) + s_a (bf16) ----
    {
        const float* Wl = oW2 + (size_t)(lh * 8) * 256 + ct * 32 + lm;
        acc = vzero;
        float f[8];
        #pragma unroll
        for (int j = 0; j < 8; ++j) f[j] = Wl[j * 256];
        #pragma unroll 4
        for (int kt = 0; kt < 16; ++kt) {
            float fn[8];
            const int kn = (kt + 1) & 15;
            #pragma unroll
            for (int j = 0; j < 8; ++j) fn[j] = Wl[(kn * 16 + j) * 256];
            bf16x8 b;
            #pragma unroll
            for (int j = 0; j < 8; ++j) b[j] = (__bf16)f[j];
            const bf16x8 a = *(const bf16x8*)&s_h[shx(lm, kt * 16 + lh * 8)];
            acc = __builtin_amdgcn_mfma_f32_32x32x16_bf16(b, a, acc, 0, 0, 0);
            #pragma unroll
            for (int j = 0; j < 8; ++j) f[j] = fn[j];
        }
        const float* bias = &ob2[ct * 32 + 4 * lh];
        float* dstg = &out[(size_t)(b0 + lm) * OUTC + ct * 32 + 4 * lh];
        #pragma unroll
        for (int g = 0; g < 4; ++g) {
            float4 fv; bf16x4 v;
            float* fp = &fv.x;
            #pragma unroll
            for (int q = 0; q < 4; ++q) {
                const float f2 = acc[g * 4 + q] + bias[8 * g + q];
                fp[q] = f2; v[q] = (__bf16)f2;
            }
            *(float4*)&dstg[8 * g] = fv;
            *(bf16x4*)&s_a[(lm << 8) + ((((ct << 2) + g) ^ lm) << 3) + 4 * lh] = v;
        }
    }
    __syncthreads();

    // ---- L3: q = s_a @ Wq + bq -> s_q (bf16) ; qb partial -> s_qb ----
    {
        const float* Wl = Wq + (size_t)(lh * 8) * 256 + ct * 32 + lm;
        acc = vzero;
        float f[8];
        #pragma unroll
        for (int j = 0; j < 8; ++j) f[j] = Wl[j * 256];
        #pragma unroll 4
        for (int kt = 0; kt < 16; ++kt) {
            float fn[8];
            const int kn = (kt + 1) & 15;
            #pragma unroll
            for (int j = 0; j < 8; ++j) fn[j] = Wl[(kn * 16 + j) * 256];
            bf16x8 b;
            #pragma unroll
            for (int j = 0; j < 8; ++j) b[j] = (__bf16)f[j];
            const bf16x8 a = *(const bf16x8*)&s_a[shx(lm, kt * 16 + lh * 8)];
            acc = __builtin_amdgcn_mfma_f32_32x32x16_bf16(b, a, acc, 0, 0, 0);
            #pragma unroll
            for (int j = 0; j < 8; ++j) f[j] = fn[j];
        }
        const int hh = ct >> 1;
        const float* bias = &bq[ct * 32 + 4 * lh];
        const float* bkp  = &bk[ct * 32 + 4 * lh];
        float part = 0.0f;
        #pragma unroll
        for (int g = 0; g < 4; ++g) {
            bf16x4 v;
            #pragma unroll
            for (int q = 0; q < 4; ++q) {
                const float f2 = acc[g * 4 + q] + bias[8 * g + q];
                part += f2 * bkp[8 * g + q];
                v[q] = (__bf16)f2;
            }
            *(bf16x4*)&s_q[(lm << 8) + ((((ct << 2) + g) ^ lm) << 3) + 4 * lh] = v;
        }
        part += __shfl_xor(part, 32, 64);
        if (lane < 32) atomicAdd(&s_qb[lm * 4 + hh], part);
    }
    __syncthreads();

    // ---- qb out ----
    if (t < 128) qbg[(size_t)(b0 + (t >> 2)) * 4 + (t & 3)] = s_qb[t];

    // ---- qk[row][h*64+d] = sum_e Wk[h][d][e]*q[row][h*64+e] via MFMA ----
    {
        const int h = wv >> 1, c2 = wv & 1;
        acc = vzero;
        #pragma unroll
        for (int kt = 0; kt < 4; ++kt) {
            const float* wk = Wk + ((size_t)(h * 64 + c2 * 32 + lm) * 64 + kt * 16 + lh * 8);
            const float4 w0 = *(const float4*)wk;
            const float4 w1 = *(const float4*)(wk + 4);
            bf16x8 b;
            b[0]=(__bf16)w0.x; b[1]=(__bf16)w0.y; b[2]=(__bf16)w0.z; b[3]=(__bf16)w0.w;
            b[4]=(__bf16)w1.x; b[5]=(__bf16)w1.y; b[6]=(__bf16)w1.z; b[7]=(__bf16)w1.w;
            const bf16x8 a = *(const bf16x8*)&s_q[shx(lm, h * 64 + kt * 16 + lh * 8)];
            acc = __builtin_amdgcn_mfma_f32_32x32x16_bf16(b, a, acc, 0, 0, 0);
        }
        float* dstg = &qkg[(size_t)(b0 + lm) * 256 + h * 64 + c2 * 32 + 4 * lh];
        #pragma unroll
        for (int g = 0; g < 4; ++g) {
            float4 fv;
            float* fp = &fv.x;
            #pragma unroll
            for (int q = 0; q < 4; ++q) fp[q] = acc[g * 4 + q];
            *(float4*)&dstg[8 * g] = fv;
        }
    }
}

// ---------------------------------------------------------------------------
// k_obj: M=128 (2 batch rows)/WG, 512 thr (8 waves), 2048 WGs, ~79 KB LDS
// -> 2 WGs/CU. Wave tile 64x64; acc 64 regs. GEMM2/3 use a DEPTH-4 circular
// B-prefetch (4 outstanding L2 loads covers ~250-cyc latency; depth-1 was
// the R6 bottleneck pinning MfmaUtil at 24%). Phases C/D vectorized.
// ---------------------------------------------------------------------------
__global__ __launch_bounds__(512, 4) void k_obj(
    const float* __restrict__ obs,  const __bf16* __restrict__ wp,
    const float* __restrict__ pb1,  const float* __restrict__ pb2,
    const float* __restrict__ pb3,  const float* __restrict__ qkg,
    const float* __restrict__ qbg,  const float* __restrict__ bv,
    const float* __restrict__ Wv,   float* __restrict__ out)
{
    __shared__ __align__(16) __bf16 s_h[128 * 256];   // 65536 B (swizzled)
    __shared__ __align__(16) char s_fp[128 * 40 * 2]; // 10240 B: feats, later p
    __bf16* s_f = (__bf16*)s_fp;
    float*  s_p = (float*)s_fp;                       // 8*64 f32 = 2048 B
    __shared__ float s_mask[128];
    __shared__ float s_qk[8 * 64];
    __shared__ float s_am[8 * 64];
    __shared__ float s_amsum[8];

    const int t  = threadIdx.x;
    const int b0 = blockIdx.x * 2;
    const int wv = t >> 6, lane = t & 63;
    const int lm = lane & 31, lh = lane >> 5;
    const int rtp = wv & 1;
    const int ct0 = (wv >> 1) * 2;
    const int row0 = rtp * 64 + lm;
    const int row1 = row0 + 32;

    // GEMM1 B-fragments: independent of staging, issue early
    bf16x8 b1[2][2];
    {
        const bf16x8* Bg = (const bf16x8*)wp + S_PW1 * 512;
        #pragma unroll
        for (int kt = 0; kt < 2; ++kt)
            #pragma unroll
            for (int c = 0; c < 2; ++c)
                b1[kt][c] = Bg[(kt * 8 + ct0 + c) * 64 + lane];
    }

    // ---- stage feats (128 x 32 bf16, stride 40) + mask ----
    {
        const int row = t >> 2, q4 = t & 3;
        const float* src = obs + (size_t)(b0 + (row >> 6)) * OBS_COLS
                               + (row & 63) * 32 + q4 * 8;
        const float4 v0 = ((const float4*)src)[0];
        const float4 v1 = ((const float4*)src)[1];
        bf16x8 o;
        o[0]=(__bf16)v0.x; o[1]=(__bf16)v0.y; o[2]=(__bf16)v0.z; o[3]=(__bf16)v0.w;
        o[4]=(__bf16)v1.x; o[5]=(__bf16)v1.y; o[6]=(__bf16)v1.z; o[7]=(__bf16)v1.w;
        *(bf16x8*)&s_f[row * 40 + q4 * 8] = o;
        if (q4 == 3) s_mask[row] = v1.w;
    }
    // stage qk for both batch rows (coalesced float4)
    if (t < 128) ((float4*)s_qk)[t] = ((const float4*)(qkg + (size_t)b0 * 256))[t];
    __syncthreads();

    f32x16 acc[2][2];
    f32x16 vzero;
    #pragma unroll
    for (int i = 0; i < 16; ++i) vzero[i] = 0.0f;

    // ========== GEMM1: h1 = relu(feats @ W1p + b1), K=32 ==========
    {
        #pragma unroll
        for (int r = 0; r < 2; ++r)
            #pragma unroll
            for (int c = 0; c < 2; ++c) acc[r][c] = vzero;
        #pragma unroll
        for (int kt = 0; kt < 2; ++kt) {
            const bf16x8 a0 = *(const bf16x8*)&s_f[row0 * 40 + kt * 16 + lh * 8];
            const bf16x8 a1 = *(const bf16x8*)&s_f[row1 * 40 + kt * 16 + lh * 8];
            acc[0][0] = __builtin_amdgcn_mfma_f32_32x32x16_bf16(b1[kt][0], a0, acc[0][0], 0, 0, 0);
            acc[0][1] = __builtin_amdgcn_mfma_f32_32x32x16_bf16(b1[kt][1], a0, acc[0][1], 0, 0, 0);
            acc[1][0] = __builtin_amdgcn_mfma_f32_32x32x16_bf16(b1[kt][0], a1, acc[1][0], 0, 0, 0);
            acc[1][1] = __builtin_amdgcn_mfma_f32_32x32x16_bf16(b1[kt][1], a1, acc[1][1], 0, 0, 0);
        }
        #pragma unroll
        for (int r = 0; r < 2; ++r) {
            const int row = r ? row1 : row0;
            #pragma unroll
            for (int c = 0; c < 2; ++c) {
                const float* bias = &pb1[(ct0 + c) * 32 + 4 * lh];
                #pragma unroll
                for (int g = 0; g < 4; ++g) {
                    bf16x4 v;
                    #pragma unroll
                    for (int q = 0; q < 4; ++q)
                        v[q] = (__bf16)fmaxf(acc[r][c][g * 4 + q] + bias[8 * g + q], 0.0f);
                    *(bf16x4*)&s_h[(row << 8) + (((((ct0 + c) << 2) + g) ^ lm) << 3) + 4 * lh] = v;
                }
            }
        }
    }
    __syncthreads();

    // ========== GEMM2: h2 = relu(h1 @ W2 + b2), K=256, depth-4 B pipe ==========
    {
        const bf16x8* Bg = (const bf16x8*)wp + S_PW2 * 512;
        #pragma unroll
        for (int r = 0; r < 2; ++r)
            #pragma unroll
            for (int c = 0; c < 2; ++c) acc[r][c] = vzero;
        bf16x8 bb[4][2];
        #pragma unroll
        for (int i = 0; i < 4; ++i) {
            bb[i][0] = Bg[(i * 8 + ct0 + 0) * 64 + lane];
            bb[i][1] = Bg[(i * 8 + ct0 + 1) * 64 + lane];
        }
        #pragma unroll
        for (int kt = 0; kt < 16; ++kt) {
            bf16x8 bl0, bl1;
            if (kt < 12) {
                bl0 = Bg[((kt + 4) * 8 + ct0 + 0) * 64 + lane];
                bl1 = Bg[((kt + 4) * 8 + ct0 + 1) * 64 + lane];
            }
            const bf16x8 a0 = *(const bf16x8*)&s_h[(row0 << 8) + (((2 * kt + lh) ^ lm) << 3)];
            const bf16x8 a1 = *(const bf16x8*)&s_h[(row1 << 8) + (((2 * kt + lh) ^ lm) << 3)];
            acc[0][0] = __builtin_amdgcn_mfma_f32_32x32x16_bf16(bb[kt & 3][0], a0, acc[0][0], 0, 0, 0);
            acc[0][1] = __builtin_amdgcn_mfma_f32_32x32x16_bf16(bb[kt & 3][1], a0, acc[0][1], 0, 0, 0);
            acc[1][0] = __builtin_amdgcn_mfma_f32_32x32x16_bf16(bb[kt & 3][0], a1, acc[1][0], 0, 0, 0);
            acc[1][1] = __builtin_amdgcn_mfma_f32_32x32x16_bf16(bb[kt & 3][1], a1, acc[1][1], 0, 0, 0);
            if (kt < 12) { bb[kt & 3][0] = bl0; bb[kt & 3][1] = bl1; }
        }
        __syncthreads();   // all reads of h1 done before in-place overwrite
        #pragma unroll
        for (int r = 0; r < 2; ++r) {
            const int row = r ? row1 : row0;
            #pragma unroll
            for (int c = 0; c < 2; ++c) {
                const float* bias = &pb2[(ct0 + c) * 32 + 4 * lh];
                #pragma unroll
                for (int g = 0; g < 4; ++g) {
                    bf16x4 v;
                    #pragma unroll
                    for (int q = 0; q < 4; ++q)
                        v[q] = (__bf16)fmaxf(acc[r][c][g * 4 + q] + bias[8 * g + q], 0.0f);
                    *(bf16x4*)&s_h[(row << 8) + (((((ct0 + c) << 2) + g) ^ lm) << 3) + 4 * lh] = v;
                }
            }
        }
    }
    __syncthreads();

    // ========== GEMM3: E = (h2 @ W3 + b3) * mask, K=256, depth-4 B pipe ==========
    {
        const bf16x8* Bg = (const bf16x8*)wp + S_PW3 * 512;
        #pragma unroll
        for (int r = 0; r < 2; ++r)
            #pragma unroll
            for (int c = 0; c < 2; ++c) acc[r][c] = vzero;
        bf16x8 bb[4][2];
        #pragma unroll
        for (int i = 0; i < 4; ++i) {
            bb[i][0] = Bg[(i * 8 + ct0 + 0) * 64 + lane];
            bb[i][1] = Bg[(i * 8 + ct0 + 1) * 64 + lane];
        }
        #pragma unroll
        for (int kt = 0; kt < 16; ++kt) {
            bf16x8 bl0, bl1;
            if (kt < 12) {
                bl0 = Bg[((kt + 4) * 8 + ct0 + 0) * 64 + lane];
                bl1 = Bg[((kt + 4) * 8 + ct0 + 1) * 64 + lane];
            }
            const bf16x8 a0 = *(const bf16x8*)&s_h[(row0 << 8) + (((2 * kt + lh) ^ lm) << 3)];
            const bf16x8 a1 = *(const bf16x8*)&s_h[(row1 << 8) + (((2 * kt + lh) ^ lm) << 3)];
            acc[0][0] = __builtin_amdgcn_mfma_f32_32x32x16_bf16(bb[kt & 3][0], a0, acc[0][0], 0, 0, 0);
            acc[0][1] = __builtin_amdgcn_mfma_f32_32x32x16_bf16(bb[kt & 3][1], a0, acc[0][1], 0, 0, 0);
            acc[1][0] = __builtin_amdgcn_mfma_f32_32x32x16_bf16(bb[kt & 3][0], a1, acc[1][0], 0, 0, 0);
            acc[1][1] = __builtin_amdgcn_mfma_f32_32x32x16_bf16(bb[kt & 3][1], a1, acc[1][1], 0, 0, 0);
            if (kt < 12) { bb[kt & 3][0] = bl0; bb[kt & 3][1] = bl1; }
        }
        __syncthreads();
        #pragma unroll
        for (int r = 0; r < 2; ++r) {
            const int row = r ? row1 : row0;
            const float mk = s_mask[row];
            #pragma unroll
            for (int c = 0; c < 2; ++c) {
                const float* bias = &pb3[(ct0 + c) * 32 + 4 * lh];
                #pragma unroll
                for (int g = 0; g < 4; ++g) {
                    bf16x4 v;
                    #pragma unroll
                    for (int q = 0; q < 4; ++q)
                        v[q] = (__bf16)((acc[r][c][g * 4 + q] + bias[8 * g + q]) * mk);
                    *(bf16x4*)&s_h[(row << 8) + (((((ct0 + c) << 2) + g) ^ lm) << 3) + 4 * lh] = v;
                }
            }
        }
    }
    __syncthreads();

    // ---- Phase B: logits + softmax (wave = one (r,h) unit; lane = object) ----
    {
        const int r = wv >> 2, h = wv & 3;
        const float qb = qbg[(size_t)(b0 + r) * 4 + h];
        const int erow = r * 64 + lane;
        float dot = 0.0f;
        #pragma unroll
        for (int d8 = 0; d8 < 8; ++d8) {
            const bf16x8 ev = *(const bf16x8*)&s_h[(erow << 8) + ((((h << 3) + d8) ^ (erow & 31)) << 3)];
            const float* kv = &s_qk[(r * 4 + h) * 64 + d8 * 8];
            #pragma unroll
            for (int j = 0; j < 8; ++j) dot += (float)ev[j] * kv[j];
        }
        const float mk = s_mask[erow];
        float logit = (dot + qb) * 0.0625f;
        if (mk == 0.0f) logit = -1.0e9f;
        float m = logit;
        #pragma unroll
        for (int off = 32; off > 0; off >>= 1) m = fmaxf(m, __shfl_xor(m, off, 64));
        const float ex = __expf(logit - m);
        float ssum = ex;
        #pragma unroll
        for (int off = 32; off > 0; off >>= 1) ssum += __shfl_xor(ssum, off, 64);
        const float am = (ex / ssum) * mk;
        s_am[(r * 4 + h) * 64 + lane] = am;
        float ams = am;
        #pragma unroll
        for (int off = 32; off > 0; off >>= 1) ams += __shfl_xor(ams, off, 64);
        if (lane == 0) s_amsum[r * 4 + h] = ams;
    }
    __syncthreads();

    // ---- Phase C: p[r][h][d] = sum_n am[n]*E[n][h*64+d] -> s_p (vectorized) ----
    {
        const int r = wv >> 2, h = wv & 3, dblk = lane >> 3, j = lane & 7;
        const int blk = (h << 3) + dblk;
        float a[8];
        #pragma unroll
        for (int dd = 0; dd < 8; ++dd) a[dd] = 0.0f;
        #pragma unroll
        for (int nn = 0; nn < 8; ++nn) {
            const int n = j * 8 + nn;
            const int row = r * 64 + n;
            const bf16x8 ev = *(const bf16x8*)&s_h[(row << 8) + ((blk ^ (row & 31)) << 3)];
            const float amv = s_am[(r * 4 + h) * 64 + n];
            #pragma unroll
            for (int dd = 0; dd < 8; ++dd) a[dd] += amv * (float)ev[dd];
        }
        #pragma unroll
        for (int off = 1; off <= 4; off <<= 1)
            #pragma unroll
            for (int dd = 0; dd < 8; ++dd) a[dd] += __shfl_xor(a[dd], off, 64);
        const float s01 = (j & 1) ? a[1] : a[0];
        const float s23 = (j & 1) ? a[3] : a[2];
        const float s45 = (j & 1) ? a[5] : a[4];
        const float s67 = (j & 1) ? a[7] : a[6];
        const float t03 = (j & 2) ? s23 : s01;
        const float t47 = (j & 2) ? s67 : s45;
        const float val = (j & 4) ? t47 : t03;
        s_p[(r * 4 + h) * 64 + dblk * 8 + j] = val;
    }
    __syncthreads();

    // ---- Phase D: out_emb = p @ Wv + amsum*bv (vectorized) ----
    {
        const int r = wv >> 2, h = wv & 3, eblk = lane >> 3, j = lane & 7;
        const float4 p0 = *(const float4*)&s_p[(r * 4 + h) * 64 + j * 8];
        const float4 p1 = *(const float4*)&s_p[(r * 4 + h) * 64 + j * 8 + 4];
        float pd[8] = {p0.x, p0.y, p0.z, p0.w, p1.x, p1.y, p1.z, p1.w};
        float a[8];
        #pragma unroll
        for (int ee = 0; ee < 8; ++ee) a[ee] = 0.0f;
        const float* wvb = Wv + (size_t)h * 4096 + eblk * 8;
        #pragma unroll
        for (int dd = 0; dd < 8; ++dd) {
            const int d = j * 8 + dd;
            const float4 w0 = *(const float4*)&wvb[d * 64];
            const float4 w1 = *(const float4*)&wvb[d * 64 + 4];
            a[0] += pd[dd] * w0.x; a[1] += pd[dd] * w0.y;
            a[2] += pd[dd] * w0.z; a[3] += pd[dd] * w0.w;
            a[4] += pd[dd] * w1.x; a[5] += pd[dd] * w1.y;
            a[6] += pd[dd] * w1.z; a[7] += pd[dd] * w1.w;
        }
        #pragma unroll
        for (int off = 1; off <= 4; off <<= 1)
            #pragma unroll
            for (int ee = 0; ee < 8; ++ee) a[ee] += __shfl_xor(a[ee], off, 64);
        const float s01 = (j & 1) ? a[1] : a[0];
        const float s23 = (j & 1) ? a[3] : a[2];
        const float s45 = (j & 1) ? a[5] : a[4];
        const float s67 = (j & 1) ? a[7] : a[6];
        const float t03 = (j & 2) ? s23 : s01;
        const float t47 = (j & 2) ? s67 : s45;
        float val = (j & 4) ? t47 : t03;
        val += s_amsum[r * 4 + h] * bv[h * 64 + lane];   // e == lane
        out[(size_t)(b0 + r) * OUTC + EMB + h * 64 + lane] = val;
    }
}

extern "C" void kernel_launch(void* const* d_in, const int* in_sizes, int n_in,
                              void* d_out, int out_size, void* d_ws, size_t ws_size,
                              hipStream_t stream)
{
    const float* obs = (const float*)d_in[0];
    const float* oW1 = (const float*)d_in[1];
    const float* ob1 = (const float*)d_in[2];
    const float* oW2 = (const float*)d_in[3];
    const float* ob2 = (const float*)d_in[4];
    const float* pW1 = (const float*)d_in[5];
    const float* pb1 = (const float*)d_in[6];
    const float* pW2 = (const float*)d_in[7];
    const float* pb2 = (const float*)d_in[8];
    const float* pW3 = (const float*)d_in[9];
    const float* pb3 = (const float*)d_in[10];
    const float* Wq  = (const float*)d_in[11];
    const float* bq  = (const float*)d_in[12];
    const float* Wk  = (const float*)d_in[13];
    const float* bk  = (const float*)d_in[14];
    const float* Wv  = (const float*)d_in[15];
    const float* bv  = (const float*)d_in[16];
    float*  out = (float*)d_out;
    float*  qkg = (float*)d_ws;
    float*  qbg = (float*)((char*)d_ws + QK_BYTES);
    __bf16* wp  = (__bf16*)((char*)d_ws + QK_BYTES + QB_BYTES);

    k_oth<<<BATCH / 32, 512, 0, stream>>>(obs, oW1, ob1, oW2, ob2, Wq, bq,
                                          Wk, bk, pW1, pW2, pW3,
                                          out, qkg, qbg, wp);
    k_obj<<<BATCH / 2, 512, 0, stream>>>(obs, wp, pb1, pb2, pb3, qkg, qbg,
                                         bv, Wv, out);
}

// Round 10
// 238.134 us; speedup vs baseline: 1.2393x; 1.2393x over previous
//
#include <hip/hip_runtime.h>

#define BATCH      4096
#define OBS_COLS   2304
#define OTH_OFF    2048
#define EMB        256
#define OUTC       512

// ws layout: qk (4096x256 f32) | qb (4096x4 f32) | packed pW slices (34 x 8KB)
#define QK_BYTES   (4096u * 256u * 4u)
#define QB_BYTES   (4096u * 4u * 4u)

typedef __bf16 bf16x8 __attribute__((ext_vector_type(8)));
typedef __bf16 bf16x4 __attribute__((ext_vector_type(4)));
typedef float  f32x16 __attribute__((ext_vector_type(16)));

// Slice bases (units of 512 bf16x8 = one 16x256 K-step slice) within wp
#define S_PW1  0
#define S_PW2  2
#define S_PW3  18
#define N_SLICE 34

// Swizzled element index into a [rows][256] bf16 LDS tile.
__device__ __forceinline__ int shx(int row, int col) {
    return (row << 8) + ((((col >> 3) ^ (row & 31)) << 3) | (col & 7));
}

// ---------------------------------------------------------------------------
// k_oth: 128 WGs x 512 thr (identical to R6 — best known).
// ---------------------------------------------------------------------------
__global__ __launch_bounds__(512, 2) void k_oth(
    const float* __restrict__ obs,
    const float* __restrict__ oW1, const float* __restrict__ ob1,
    const float* __restrict__ oW2, const float* __restrict__ ob2,
    const float* __restrict__ Wq,  const float* __restrict__ bq,
    const float* __restrict__ Wk,  const float* __restrict__ bk,
    const float* __restrict__ pW1, const float* __restrict__ pW2,
    const float* __restrict__ pW3,
    float* __restrict__ out, float* __restrict__ qkg,
    float* __restrict__ qbg, __bf16* __restrict__ wp)
{
    __shared__ __align__(16) __bf16 s_a[32 * 256];   // 16 KB
    __shared__ __align__(16) __bf16 s_h[32 * 256];   // 16 KB
    __shared__ __align__(16) __bf16 s_q[32 * 256];   // 16 KB
    __shared__ float s_qb[32 * 4];

    const int t  = threadIdx.x;
    const int b0 = blockIdx.x * 32;
    const int wv = t >> 6, lane = t & 63;
    const int lm = lane & 31, lh = lane >> 5;
    const int ct = wv;                 // col tile 0..7

    // ---- pack pW slices for k_obj (WGs 0..33) ----
    if (blockIdx.x < N_SLICE) {
        const int s = blockIdx.x;
        int kt; const float* W; int isW1 = 0;
        if      (s < S_PW2) { kt = s;         W = pW1; isW1 = 1; }
        else if (s < S_PW3) { kt = s - S_PW2; W = pW2; }
        else                { kt = s - S_PW3; W = pW3; }
        const int kbase = kt * 16 + lh * 8;
        const int n     = (t >> 6) * 32 + lm;
        bf16x8 v;
        #pragma unroll
        for (int j = 0; j < 8; ++j) {
            const int k = kbase + j;
            const float f = (isW1 && k >= 31) ? 0.0f : W[k * 256 + n];
            v[j] = (__bf16)f;
        }
        ((bf16x8*)wp)[(size_t)s * 512 + t] = v;
    }

    // ---- stage 32 rows x 256 cols (fp32 -> bf16, swizzled) ----
    #pragma unroll
    for (int i = 0; i < 2; ++i) {
        const int c = i * 512 + t;
        const int row = c >> 5, seg = c & 31;
        const float* src = obs + (size_t)(b0 + row) * OBS_COLS + OTH_OFF + seg * 8;
        const float4 v0 = ((const float4*)src)[0];
        const float4 v1 = ((const float4*)src)[1];
        bf16x8 o;
        o[0]=(__bf16)v0.x; o[1]=(__bf16)v0.y; o[2]=(__bf16)v0.z; o[3]=(__bf16)v0.w;
        o[4]=(__bf16)v1.x; o[5]=(__bf16)v1.y; o[6]=(__bf16)v1.z; o[7]=(__bf16)v1.w;
        *(bf16x8*)&s_a[shx(row, seg * 8)] = o;
    }
    if (t < 128) s_qb[t] = 0.0f;
    __syncthreads();

    f32x16 acc;
    f32x16 vzero;
    #pragma unroll
    for (int i = 0; i < 16; ++i) vzero[i] = 0.0f;

    // ---- L1: h = relu(A @ oW1 + ob1); B direct from fp32, depth-1 rot ----
    {
        const float* Wl = oW1 + (size_t)(lh * 8) * 256 + ct * 32 + lm;
        acc = vzero;
        float f[8];
        #pragma unroll
        for (int j = 0; j < 8; ++j) f[j] = Wl[j * 256];
        #pragma unroll 4
        for (int kt = 0; kt < 16; ++kt) {
            float fn[8];
            const int kn = (kt + 1) & 15;
            #pragma unroll
            for (int j = 0; j < 8; ++j) fn[j] = Wl[(kn * 16 + j) * 256];
            bf16x8 b;
            #pragma unroll
            for (int j = 0; j < 8; ++j) b[j] = (__bf16)f[j];
            const bf16x8 a = *(const bf16x8*)&s_a[shx(lm, kt * 16 + lh * 8)];
            acc = __builtin_amdgcn_mfma_f32_32x32x16_bf16(b, a, acc, 0, 0, 0);
            #pragma unroll
            for (int j = 0; j < 8; ++j) f[j] = fn[j];
        }
        const float* bias = &ob1[ct * 32 + 4 * lh];
        #pragma unroll
        for (int g = 0; g < 4; ++g) {
            bf16x4 v;
            #pragma unroll
            for (int q = 0; q < 4; ++q)
                v[q] = (__bf16)fmaxf(acc[g * 4 + q] + bias[8 * g + q], 0.0f);
            *(bf16x4*)&s_h[(lm << 8) + ((((ct << 2) + g) ^ lm) << 3) + 4 * lh] = v;
        }
    }
    __syncthreads();

    // ---- L2: e = s_h @ oW2 + ob2 -> out (fp32) + s_a (bf16) ----
    {
        const float* Wl = oW2 + (size_t)(lh * 8) * 256 + ct * 32 + lm;
        acc = vzero;
        float f[8];
        #pragma unroll
        for (int j = 0; j < 8; ++j) f[j] = Wl[j * 256];
        #pragma unroll 4
        for (int kt = 0; kt < 16; ++kt) {
            float fn[8];
            const int kn = (kt + 1) & 15;
            #pragma unroll
            for (int j = 0; j < 8; ++j) fn[j] = Wl[(kn * 16 + j) * 256];
            bf16x8 b;
            #pragma unroll
            for (int j = 0; j < 8; ++j) b[j] = (__bf16)f[j];
            const bf16x8 a = *(const bf16x8*)&s_h[shx(lm, kt * 16 + lh * 8)];
            acc = __builtin_amdgcn_mfma_f32_32x32x16_bf16(b, a, acc, 0, 0, 0);
            #pragma unroll
            for (int j = 0; j < 8; ++j) f[j] = fn[j];
        }
        const float* bias = &ob2[ct * 32 + 4 * lh];
        float* dstg = &out[(size_t)(b0 + lm) * OUTC + ct * 32 + 4 * lh];
        #pragma unroll
        for (int g = 0; g < 4; ++g) {
            float4 fv; bf16x4 v;
            float* fp = &fv.x;
            #pragma unroll
            for (int q = 0; q < 4; ++q) {
                const float f2 = acc[g * 4 + q] + bias[8 * g + q];
                fp[q] = f2; v[q] = (__bf16)f2;
            }
            *(float4*)&dstg[8 * g] = fv;
            *(bf16x4*)&s_a[(lm << 8) + ((((ct << 2) + g) ^ lm) << 3) + 4 * lh] = v;
        }
    }
    __syncthreads();

    // ---- L3: q = s_a @ Wq + bq -> s_q (bf16) ; qb partial -> s_qb ----
    {
        const float* Wl = Wq + (size_t)(lh * 8) * 256 + ct * 32 + lm;
        acc = vzero;
        float f[8];
        #pragma unroll
        for (int j = 0; j < 8; ++j) f[j] = Wl[j * 256];
        #pragma unroll 4
        for (int kt = 0; kt < 16; ++kt) {
            float fn[8];
            const int kn = (kt + 1) & 15;
            #pragma unroll
            for (int j = 0; j < 8; ++j) fn[j] = Wl[(kn * 16 + j) * 256];
            bf16x8 b;
            #pragma unroll
            for (int j = 0; j < 8; ++j) b[j] = (__bf16)f[j];
            const bf16x8 a = *(const bf16x8*)&s_a[shx(lm, kt * 16 + lh * 8)];
            acc = __builtin_amdgcn_mfma_f32_32x32x16_bf16(b, a, acc, 0, 0, 0);
            #pragma unroll
            for (int j = 0; j < 8; ++j) f[j] = fn[j];
        }
        const int hh = ct >> 1;
        const float* bias = &bq[ct * 32 + 4 * lh];
        const float* bkp  = &bk[ct * 32 + 4 * lh];
        float part = 0.0f;
        #pragma unroll
        for (int g = 0; g < 4; ++g) {
            bf16x4 v;
            #pragma unroll
            for (int q = 0; q < 4; ++q) {
                const float f2 = acc[g * 4 + q] + bias[8 * g + q];
                part += f2 * bkp[8 * g + q];
                v[q] = (__bf16)f2;
            }
            *(bf16x4*)&s_q[(lm << 8) + ((((ct << 2) + g) ^ lm) << 3) + 4 * lh] = v;
        }
        part += __shfl_xor(part, 32, 64);
        if (lane < 32) atomicAdd(&s_qb[lm * 4 + hh], part);
    }
    __syncthreads();

    // ---- qb out ----
    if (t < 128) qbg[(size_t)(b0 + (t >> 2)) * 4 + (t & 3)] = s_qb[t];

    // ---- qk[row][h*64+d] = sum_e Wk[h][d][e]*q[row][h*64+e] via MFMA ----
    {
        const int h = wv >> 1, c2 = wv & 1;
        acc = vzero;
        #pragma unroll
        for (int kt = 0; kt < 4; ++kt) {
            const float* wk = Wk + ((size_t)(h * 64 + c2 * 32 + lm) * 64 + kt * 16 + lh * 8);
            const float4 w0 = *(const float4*)wk;
            const float4 w1 = *(const float4*)(wk + 4);
            bf16x8 b;
            b[0]=(__bf16)w0.x; b[1]=(__bf16)w0.y; b[2]=(__bf16)w0.z; b[3]=(__bf16)w0.w;
            b[4]=(__bf16)w1.x; b[5]=(__bf16)w1.y; b[6]=(__bf16)w1.z; b[7]=(__bf16)w1.w;
            const bf16x8 a = *(const bf16x8*)&s_q[shx(lm, h * 64 + kt * 16 + lh * 8)];
            acc = __builtin_amdgcn_mfma_f32_32x32x16_bf16(b, a, acc, 0, 0, 0);
        }
        float* dstg = &qkg[(size_t)(b0 + lm) * 256 + h * 64 + c2 * 32 + 4 * lh];
        #pragma unroll
        for (int g = 0; g < 4; ++g) {
            float4 fv;
            float* fp = &fv.x;
            #pragma unroll
            for (int q = 0; q < 4; ++q) fp[q] = acc[g * 4 + q];
            *(float4*)&dstg[8 * g] = fv;
        }
    }
}

// ---------------------------------------------------------------------------
// k_obj: R6 structure (M=128, 512 thr, 2 WG/CU, depth-1 B rotation) plus:
//  - acc initialized with bias (kills 64 v_add/GEMM/wave)
//  - next GEMM's first B-pair prefetched before the preceding barrier
//  - Phases C/D vectorized (bf16x8/float4 + xor-shuffle reduction)
// ---------------------------------------------------------------------------
__global__ __launch_bounds__(512, 4) void k_obj(
    const float* __restrict__ obs,  const __bf16* __restrict__ wp,
    const float* __restrict__ pb1,  const float* __restrict__ pb2,
    const float* __restrict__ pb3,  const float* __restrict__ qkg,
    const float* __restrict__ qbg,  const float* __restrict__ bv,
    const float* __restrict__ Wv,   float* __restrict__ out)
{
    __shared__ __align__(16) __bf16 s_h[128 * 256];   // 65536 B (swizzled)
    __shared__ __align__(16) char s_fp[128 * 40 * 2]; // 10240 B: feats, later p
    __bf16* s_f = (__bf16*)s_fp;
    float*  s_p = (float*)s_fp;                       // 8*64 f32 = 2048 B
    __shared__ float s_mask[128];
    __shared__ float s_qk[8 * 64];
    __shared__ float s_am[8 * 64];
    __shared__ float s_amsum[8];

    const int t  = threadIdx.x;
    const int b0 = blockIdx.x * 2;
    const int wv = t >> 6, lane = t & 63;
    const int lm = lane & 31, lh = lane >> 5;
    const int rtp = wv & 1;
    const int ct0 = (wv >> 1) * 2;
    const int row0 = rtp * 64 + lm;
    const int row1 = row0 + 32;

    // GEMM1 B-fragments: independent of staging, issue early
    bf16x8 b1[2][2];
    {
        const bf16x8* Bg = (const bf16x8*)wp + S_PW1 * 512;
        #pragma unroll
        for (int kt = 0; kt < 2; ++kt)
            #pragma unroll
            for (int c = 0; c < 2; ++c)
                b1[kt][c] = Bg[(kt * 8 + ct0 + c) * 64 + lane];
    }

    // ---- stage feats (128 x 32 bf16, stride 40) + mask ----
    {
        const int row = t >> 2, q4 = t & 3;
        const float* src = obs + (size_t)(b0 + (row >> 6)) * OBS_COLS
                               + (row & 63) * 32 + q4 * 8;
        const float4 v0 = ((const float4*)src)[0];
        const float4 v1 = ((const float4*)src)[1];
        bf16x8 o;
        o[0]=(__bf16)v0.x; o[1]=(__bf16)v0.y; o[2]=(__bf16)v0.z; o[3]=(__bf16)v0.w;
        o[4]=(__bf16)v1.x; o[5]=(__bf16)v1.y; o[6]=(__bf16)v1.z; o[7]=(__bf16)v1.w;
        *(bf16x8*)&s_f[row * 40 + q4 * 8] = o;
        if (q4 == 3) s_mask[row] = v1.w;
    }
    // stage qk for both batch rows (coalesced float4)
    if (t < 128) ((float4*)s_qk)[t] = ((const float4*)(qkg + (size_t)b0 * 256))[t];
    __syncthreads();

    f32x16 acc[2][2];

    // ========== GEMM1: h1 = relu(feats @ W1p + b1), K=32 ==========
    {
        // bias-init acc
        #pragma unroll
        for (int c = 0; c < 2; ++c) {
            #pragma unroll
            for (int g = 0; g < 4; ++g) {
                const float4 bv4 = *(const float4*)&pb1[(ct0 + c) * 32 + 4 * lh + 8 * g];
                acc[0][c][g*4+0] = bv4.x; acc[0][c][g*4+1] = bv4.y;
                acc[0][c][g*4+2] = bv4.z; acc[0][c][g*4+3] = bv4.w;
            }
            acc[1][c] = acc[0][c];
        }
        #pragma unroll
        for (int kt = 0; kt < 2; ++kt) {
            const bf16x8 a0 = *(const bf16x8*)&s_f[row0 * 40 + kt * 16 + lh * 8];
            const bf16x8 a1 = *(const bf16x8*)&s_f[row1 * 40 + kt * 16 + lh * 8];
            acc[0][0] = __builtin_amdgcn_mfma_f32_32x32x16_bf16(b1[kt][0], a0, acc[0][0], 0, 0, 0);
            acc[0][1] = __builtin_amdgcn_mfma_f32_32x32x16_bf16(b1[kt][1], a0, acc[0][1], 0, 0, 0);
            acc[1][0] = __builtin_amdgcn_mfma_f32_32x32x16_bf16(b1[kt][0], a1, acc[1][0], 0, 0, 0);
            acc[1][1] = __builtin_amdgcn_mfma_f32_32x32x16_bf16(b1[kt][1], a1, acc[1][1], 0, 0, 0);
        }
        #pragma unroll
        for (int r = 0; r < 2; ++r) {
            const int row = r ? row1 : row0;
            #pragma unroll
            for (int c = 0; c < 2; ++c) {
                #pragma unroll
                for (int g = 0; g < 4; ++g) {
                    bf16x4 v;
                    #pragma unroll
                    for (int q = 0; q < 4; ++q)
                        v[q] = (__bf16)fmaxf(acc[r][c][g * 4 + q], 0.0f);
                    *(bf16x4*)&s_h[(row << 8) + (((((ct0 + c) << 2) + g) ^ lm) << 3) + 4 * lh] = v;
                }
            }
        }
    }
    // prefetch GEMM2's first B-pair across the barrier
    const bf16x8* Bg2 = (const bf16x8*)wp + S_PW2 * 512;
    bf16x8 p20 = Bg2[(ct0 + 0) * 64 + lane];
    bf16x8 p21 = Bg2[(ct0 + 1) * 64 + lane];
    __syncthreads();

    // ========== GEMM2: h2 = relu(h1 @ W2 + b2), K=256, depth-1 rot ==========
    {
        #pragma unroll
        for (int c = 0; c < 2; ++c) {
            #pragma unroll
            for (int g = 0; g < 4; ++g) {
                const float4 bv4 = *(const float4*)&pb2[(ct0 + c) * 32 + 4 * lh + 8 * g];
                acc[0][c][g*4+0] = bv4.x; acc[0][c][g*4+1] = bv4.y;
                acc[0][c][g*4+2] = bv4.z; acc[0][c][g*4+3] = bv4.w;
            }
            acc[1][c] = acc[0][c];
        }
        bf16x8 bc0 = p20, bc1 = p21;
        #pragma unroll 4
        for (int kt = 0; kt < 16; ++kt) {
            const int kn = (kt + 1) & 15;
            const bf16x8 bn0 = Bg2[(kn * 8 + ct0 + 0) * 64 + lane];
            const bf16x8 bn1 = Bg2[(kn * 8 + ct0 + 1) * 64 + lane];
            const bf16x8 a0 = *(const bf16x8*)&s_h[(row0 << 8) + (((2 * kt + lh) ^ lm) << 3)];
            const bf16x8 a1 = *(const bf16x8*)&s_h[(row1 << 8) + (((2 * kt + lh) ^ lm) << 3)];
            acc[0][0] = __builtin_amdgcn_mfma_f32_32x32x16_bf16(bc0, a0, acc[0][0], 0, 0, 0);
            acc[0][1] = __builtin_amdgcn_mfma_f32_32x32x16_bf16(bc1, a0, acc[0][1], 0, 0, 0);
            acc[1][0] = __builtin_amdgcn_mfma_f32_32x32x16_bf16(bc0, a1, acc[1][0], 0, 0, 0);
            acc[1][1] = __builtin_amdgcn_mfma_f32_32x32x16_bf16(bc1, a1, acc[1][1], 0, 0, 0);
            bc0 = bn0; bc1 = bn1;
        }
        __syncthreads();   // all reads of h1 done before in-place overwrite
        #pragma unroll
        for (int r = 0; r < 2; ++r) {
            const int row = r ? row1 : row0;
            #pragma unroll
            for (int c = 0; c < 2; ++c) {
                #pragma unroll
                for (int g = 0; g < 4; ++g) {
                    bf16x4 v;
                    #pragma unroll
                    for (int q = 0; q < 4; ++q)
                        v[q] = (__bf16)fmaxf(acc[r][c][g * 4 + q], 0.0f);
                    *(bf16x4*)&s_h[(row << 8) + (((((ct0 + c) << 2) + g) ^ lm) << 3) + 4 * lh] = v;
                }
            }
        }
    }
    // prefetch GEMM3's first B-pair across the barrier
    const bf16x8* Bg3 = (const bf16x8*)wp + S_PW3 * 512;
    bf16x8 p30 = Bg3[(ct0 + 0) * 64 + lane];
    bf16x8 p31 = Bg3[(ct0 + 1) * 64 + lane];
    __syncthreads();

    // ========== GEMM3: E = (h2 @ W3 + b3) * mask, K=256, depth-1 rot ==========
    {
        #pragma unroll
        for (int c = 0; c < 2; ++c) {
            #pragma unroll
            for (int g = 0; g < 4; ++g) {
                const float4 bv4 = *(const float4*)&pb3[(ct0 + c) * 32 + 4 * lh + 8 * g];
                acc[0][c][g*4+0] = bv4.x; acc[0][c][g*4+1] = bv4.y;
                acc[0][c][g*4+2] = bv4.z; acc[0][c][g*4+3] = bv4.w;
            }
            acc[1][c] = acc[0][c];
        }
        bf16x8 bc0 = p30, bc1 = p31;
        #pragma unroll 4
        for (int kt = 0; kt < 16; ++kt) {
            const int kn = (kt + 1) & 15;
            const bf16x8 bn0 = Bg3[(kn * 8 + ct0 + 0) * 64 + lane];
            const bf16x8 bn1 = Bg3[(kn * 8 + ct0 + 1) * 64 + lane];
            const bf16x8 a0 = *(const bf16x8*)&s_h[(row0 << 8) + (((2 * kt + lh) ^ lm) << 3)];
            const bf16x8 a1 = *(const bf16x8*)&s_h[(row1 << 8) + (((2 * kt + lh) ^ lm) << 3)];
            acc[0][0] = __builtin_amdgcn_mfma_f32_32x32x16_bf16(bc0, a0, acc[0][0], 0, 0, 0);
            acc[0][1] = __builtin_amdgcn_mfma_f32_32x32x16_bf16(bc1, a0, acc[0][1], 0, 0, 0);
            acc[1][0] = __builtin_amdgcn_mfma_f32_32x32x16_bf16(bc0, a1, acc[1][0], 0, 0, 0);
            acc[1][1] = __builtin_amdgcn_mfma_f32_32x32x16_bf16(bc1, a1, acc[1][1], 0, 0, 0);
            bc0 = bn0; bc1 = bn1;
        }
        __syncthreads();
        #pragma unroll
        for (int r = 0; r < 2; ++r) {
            const int row = r ? row1 : row0;
            const float mk = s_mask[row];
            #pragma unroll
            for (int c = 0; c < 2; ++c) {
                #pragma unroll
                for (int g = 0; g < 4; ++g) {
                    bf16x4 v;
                    #pragma unroll
                    for (int q = 0; q < 4; ++q)
                        v[q] = (__bf16)(acc[r][c][g * 4 + q] * mk);
                    *(bf16x4*)&s_h[(row << 8) + (((((ct0 + c) << 2) + g) ^ lm) << 3) + 4 * lh] = v;
                }
            }
        }
    }
    __syncthreads();

    // ---- Phase B: logits + softmax (wave = one (r,h) unit; lane = object) ----
    {
        const int r = wv >> 2, h = wv & 3;
        const float qb = qbg[(size_t)(b0 + r) * 4 + h];
        const int erow = r * 64 + lane;
        float dot = 0.0f;
        #pragma unroll
        for (int d8 = 0; d8 < 8; ++d8) {
            const bf16x8 ev = *(const bf16x8*)&s_h[(erow << 8) + ((((h << 3) + d8) ^ (erow & 31)) << 3)];
            const float* kv = &s_qk[(r * 4 + h) * 64 + d8 * 8];
            #pragma unroll
            for (int j = 0; j < 8; ++j) dot += (float)ev[j] * kv[j];
        }
        const float mk = s_mask[erow];
        float logit = (dot + qb) * 0.0625f;
        if (mk == 0.0f) logit = -1.0e9f;
        float m = logit;
        #pragma unroll
        for (int off = 32; off > 0; off >>= 1) m = fmaxf(m, __shfl_xor(m, off, 64));
        const float ex = __expf(logit - m);
        float ssum = ex;
        #pragma unroll
        for (int off = 32; off > 0; off >>= 1) ssum += __shfl_xor(ssum, off, 64);
        const float am = (ex / ssum) * mk;
        s_am[(r * 4 + h) * 64 + lane] = am;
        float ams = am;
        #pragma unroll
        for (int off = 32; off > 0; off >>= 1) ams += __shfl_xor(ams, off, 64);
        if (lane == 0) s_amsum[r * 4 + h] = ams;
    }
    __syncthreads();

    // ---- Phase C: p[r][h][d] = sum_n am[n]*E[n][h*64+d] -> s_p (vectorized) ----
    {
        const int r = wv >> 2, h = wv & 3, dblk = lane >> 3, j = lane & 7;
        const int blk = (h << 3) + dblk;
        float a[8];
        #pragma unroll
        for (int dd = 0; dd < 8; ++dd) a[dd] = 0.0f;
        #pragma unroll
        for (int nn = 0; nn < 8; ++nn) {
            const int n = j * 8 + nn;
            const int row = r * 64 + n;
            const bf16x8 ev = *(const bf16x8*)&s_h[(row << 8) + ((blk ^ (row & 31)) << 3)];
            const float amv = s_am[(r * 4 + h) * 64 + n];
            #pragma unroll
            for (int dd = 0; dd < 8; ++dd) a[dd] += amv * (float)ev[dd];
        }
        #pragma unroll
        for (int off = 1; off <= 4; off <<= 1)
            #pragma unroll
            for (int dd = 0; dd < 8; ++dd) a[dd] += __shfl_xor(a[dd], off, 64);
        const float s01 = (j & 1) ? a[1] : a[0];
        const float s23 = (j & 1) ? a[3] : a[2];
        const float s45 = (j & 1) ? a[5] : a[4];
        const float s67 = (j & 1) ? a[7] : a[6];
        const float t03 = (j & 2) ? s23 : s01;
        const float t47 = (j & 2) ? s67 : s45;
        const float val = (j & 4) ? t47 : t03;
        s_p[(r * 4 + h) * 64 + dblk * 8 + j] = val;
    }
    __syncthreads();

    // ---- Phase D: out_emb = p @ Wv + amsum*bv (vectorized) ----
    {
        const int r = wv >> 2, h = wv & 3, eblk = lane >> 3, j = lane & 7;
        const float4 p0 = *(const float4*)&s_p[(r * 4 + h) * 64 + j * 8];
        const float4 p1 = *(const float4*)&s_p[(r * 4 + h) * 64 + j * 8 + 4];
        float pd[8] = {p0.x, p0.y, p0.z, p0.w, p1.x, p1.y, p1.z, p1.w};
        float a[8];
        #pragma unroll
        for (int ee = 0; ee < 8; ++ee) a[ee] = 0.0f;
        const float* wvb = Wv + (size_t)h * 4096 + eblk * 8;
        #pragma unroll
        for (int dd = 0; dd < 8; ++dd) {
            const int d = j * 8 + dd;
            const float4 w0 = *(const float4*)&wvb[d * 64];
            const float4 w1 = *(const float4*)&wvb[d * 64 + 4];
            a[0] += pd[dd] * w0.x; a[1] += pd[dd] * w0.y;
            a[2] += pd[dd] * w0.z; a[3] += pd[dd] * w0.w;
            a[4] += pd[dd] * w1.x; a[5] += pd[dd] * w1.y;
            a[6] += pd[dd] * w1.z; a[7] += pd[dd] * w1.w;
        }
        #pragma unroll
        for (int off = 1; off <= 4; off <<= 1)
            #pragma unroll
            for (int ee = 0; ee < 8; ++ee) a[ee] += __shfl_xor(a[ee], off, 64);
        const float s01 = (j & 1) ? a[1] : a[0];
        const float s23 = (j & 1) ? a[3] : a[2];
        const float s45 = (j & 1) ? a[5] : a[4];
        const float s67 = (j & 1) ? a[7] : a[6];
        const float t03 = (j & 2) ? s23 : s01;
        const float t47 = (j & 2) ? s67 : s45;
        float val = (j & 4) ? t47 : t03;
        val += s_amsum[r * 4 + h] * bv[h * 64 + lane];   // e == lane
        out[(size_t)(b0 + r) * OUTC + EMB + h * 64 + lane] = val;
    }
}

extern "C" void kernel_launch(void* const* d_in, const int* in_sizes, int n_in,
                              void* d_out, int out_size, void* d_ws, size_t ws_size,
                              hipStream_t stream)
{
    const float* obs = (const float*)d_in[0];
    const float* oW1 = (const float*)d_in[1];
    const float* ob1 = (const float*)d_in[2];
    const float* oW2 = (const float*)d_in[3];
    const float* ob2 = (const float*)d_in[4];
    const float* pW1 = (const float*)d_in[5];
    const float* pb1 = (const float*)d_in[6];
    const float* pW2 = (const float*)d_in[7];
    const float* pb2 = (const float*)d_in[8];
    const float* pW3 = (const float*)d_in[9];
    const float* pb3 = (const float*)d_in[10];
    const float* Wq  = (const float*)d_in[11];
    const float* bq  = (const float*)d_in[12];
    const float* Wk  = (const float*)d_in[13];
    const float* bk  = (const float*)d_in[14];
    const float* Wv  = (const float*)d_in[15];
    const float* bv  = (const float*)d_in[16];
    float*  out = (float*)d_out;
    float*  qkg = (float*)d_ws;
    float*  qbg = (float*)((char*)d_ws + QK_BYTES);
    __bf16* wp  = (__bf16*)((char*)d_ws + QK_BYTES + QB_BYTES);

    k_oth<<<BATCH / 32, 512, 0, stream>>>(obs, oW1, ob1, oW2, ob2, Wq, bq,
                                          Wk, bk, pW1, pW2, pW3,
                                          out, qkg, qbg, wp);
    k_obj<<<BATCH / 2, 512, 0, stream>>>(obs, wp, pb1, pb2, pb3, qkg, qbg,
                                         bv, Wv, out);
}

// Round 11
// 226.421 us; speedup vs baseline: 1.3035x; 1.0517x over previous
//
#include <hip/hip_runtime.h>

#define BATCH      4096
#define OBS_COLS   2304
#define OTH_OFF    2048
#define EMB        256
#define OUTC       512

// ws layout: qk (4096x256 f32) | qb (4096x4 f32) | packed pW slices (34 x 8KB)
#define QK_BYTES   (4096u * 256u * 4u)
#define QB_BYTES   (4096u * 4u * 4u)

typedef __bf16 bf16x8 __attribute__((ext_vector_type(8)));
typedef __bf16 bf16x4 __attribute__((ext_vector_type(4)));
typedef float  f32x16 __attribute__((ext_vector_type(16)));

// Slice bases (units of 512 bf16x8 = one 16x256 K-step slice) within wp
#define S_PW1  0
#define S_PW2  2
#define S_PW3  18
#define N_SLICE 34

// Swizzled element index into a [rows][256] bf16 LDS tile.
__device__ __forceinline__ int shx(int row, int col) {
    return (row << 8) + ((((col >> 3) ^ (row & 31)) << 3) | (col & 7));
}

// ---------------------------------------------------------------------------
// k_oth: 128 WGs x 512 thr (identical to R6/R10 — best known).
// ---------------------------------------------------------------------------
__global__ __launch_bounds__(512, 2) void k_oth(
    const float* __restrict__ obs,
    const float* __restrict__ oW1, const float* __restrict__ ob1,
    const float* __restrict__ oW2, const float* __restrict__ ob2,
    const float* __restrict__ Wq,  const float* __restrict__ bq,
    const float* __restrict__ Wk,  const float* __restrict__ bk,
    const float* __restrict__ pW1, const float* __restrict__ pW2,
    const float* __restrict__ pW3,
    float* __restrict__ out, float* __restrict__ qkg,
    float* __restrict__ qbg, __bf16* __restrict__ wp)
{
    __shared__ __align__(16) __bf16 s_a[32 * 256];   // 16 KB
    __shared__ __align__(16) __bf16 s_h[32 * 256];   // 16 KB
    __shared__ __align__(16) __bf16 s_q[32 * 256];   // 16 KB
    __shared__ float s_qb[32 * 4];

    const int t  = threadIdx.x;
    const int b0 = blockIdx.x * 32;
    const int wv = t >> 6, lane = t & 63;
    const int lm = lane & 31, lh = lane >> 5;
    const int ct = wv;                 // col tile 0..7

    // ---- pack pW slices for k_obj (WGs 0..33) ----
    if (blockIdx.x < N_SLICE) {
        const int s = blockIdx.x;
        int kt; const float* W; int isW1 = 0;
        if      (s < S_PW2) { kt = s;         W = pW1; isW1 = 1; }
        else if (s < S_PW3) { kt = s - S_PW2; W = pW2; }
        else                { kt = s - S_PW3; W = pW3; }
        const int kbase = kt * 16 + lh * 8;
        const int n     = (t >> 6) * 32 + lm;
        bf16x8 v;
        #pragma unroll
        for (int j = 0; j < 8; ++j) {
            const int k = kbase + j;
            const float f = (isW1 && k >= 31) ? 0.0f : W[k * 256 + n];
            v[j] = (__bf16)f;
        }
        ((bf16x8*)wp)[(size_t)s * 512 + t] = v;
    }

    // ---- stage 32 rows x 256 cols (fp32 -> bf16, swizzled) ----
    #pragma unroll
    for (int i = 0; i < 2; ++i) {
        const int c = i * 512 + t;
        const int row = c >> 5, seg = c & 31;
        const float* src = obs + (size_t)(b0 + row) * OBS_COLS + OTH_OFF + seg * 8;
        const float4 v0 = ((const float4*)src)[0];
        const float4 v1 = ((const float4*)src)[1];
        bf16x8 o;
        o[0]=(__bf16)v0.x; o[1]=(__bf16)v0.y; o[2]=(__bf16)v0.z; o[3]=(__bf16)v0.w;
        o[4]=(__bf16)v1.x; o[5]=(__bf16)v1.y; o[6]=(__bf16)v1.z; o[7]=(__bf16)v1.w;
        *(bf16x8*)&s_a[shx(row, seg * 8)] = o;
    }
    if (t < 128) s_qb[t] = 0.0f;
    __syncthreads();

    f32x16 acc;
    f32x16 vzero;
    #pragma unroll
    for (int i = 0; i < 16; ++i) vzero[i] = 0.0f;

    // ---- L1: h = relu(A @ oW1 + ob1); B direct from fp32, depth-1 rot ----
    {
        const float* Wl = oW1 + (size_t)(lh * 8) * 256 + ct * 32 + lm;
        acc = vzero;
        float f[8];
        #pragma unroll
        for (int j = 0; j < 8; ++j) f[j] = Wl[j * 256];
        #pragma unroll 4
        for (int kt = 0; kt < 16; ++kt) {
            float fn[8];
            const int kn = (kt + 1) & 15;
            #pragma unroll
            for (int j = 0; j < 8; ++j) fn[j] = Wl[(kn * 16 + j) * 256];
            bf16x8 b;
            #pragma unroll
            for (int j = 0; j < 8; ++j) b[j] = (__bf16)f[j];
            const bf16x8 a = *(const bf16x8*)&s_a[shx(lm, kt * 16 + lh * 8)];
            acc = __builtin_amdgcn_mfma_f32_32x32x16_bf16(b, a, acc, 0, 0, 0);
            #pragma unroll
            for (int j = 0; j < 8; ++j) f[j] = fn[j];
        }
        const float* bias = &ob1[ct * 32 + 4 * lh];
        #pragma unroll
        for (int g = 0; g < 4; ++g) {
            bf16x4 v;
            #pragma unroll
            for (int q = 0; q < 4; ++q)
                v[q] = (__bf16)fmaxf(acc[g * 4 + q] + bias[8 * g + q], 0.0f);
            *(bf16x4*)&s_h[(lm << 8) + ((((ct << 2) + g) ^ lm) << 3) + 4 * lh] = v;
        }
    }
    __syncthreads();

    // ---- L2: e = s_h @ oW2 + ob2 -> out (fp32) + s_a (bf16) ----
    {
        const float* Wl = oW2 + (size_t)(lh * 8) * 256 + ct * 32 + lm;
        acc = vzero;
        float f[8];
        #pragma unroll
        for (int j = 0; j < 8; ++j) f[j] = Wl[j * 256];
        #pragma unroll 4
        for (int kt = 0; kt < 16; ++kt) {
            float fn[8];
            const int kn = (kt + 1) & 15;
            #pragma unroll
            for (int j = 0; j < 8; ++j) fn[j] = Wl[(kn * 16 + j) * 256];
            bf16x8 b;
            #pragma unroll
            for (int j = 0; j < 8; ++j) b[j] = (__bf16)f[j];
            const bf16x8 a = *(const bf16x8*)&s_h[shx(lm, kt * 16 + lh * 8)];
            acc = __builtin_amdgcn_mfma_f32_32x32x16_bf16(b, a, acc, 0, 0, 0);
            #pragma unroll
            for (int j = 0; j < 8; ++j) f[j] = fn[j];
        }
        const float* bias = &ob2[ct * 32 + 4 * lh];
        float* dstg = &out[(size_t)(b0 + lm) * OUTC + ct * 32 + 4 * lh];
        #pragma unroll
        for (int g = 0; g < 4; ++g) {
            float4 fv; bf16x4 v;
            float* fp = &fv.x;
            #pragma unroll
            for (int q = 0; q < 4; ++q) {
                const float f2 = acc[g * 4 + q] + bias[8 * g + q];
                fp[q] = f2; v[q] = (__bf16)f2;
            }
            *(float4*)&dstg[8 * g] = fv;
            *(bf16x4*)&s_a[(lm << 8) + ((((ct << 2) + g) ^ lm) << 3) + 4 * lh] = v;
        }
    }
    __syncthreads();

    // ---- L3: q = s_a @ Wq + bq -> s_q (bf16) ; qb partial -> s_qb ----
    {
        const float* Wl = Wq + (size_t)(lh * 8) * 256 + ct * 32 + lm;
        acc = vzero;
        float f[8];
        #pragma unroll
        for (int j = 0; j < 8; ++j) f[j] = Wl[j * 256];
        #pragma unroll 4
        for (int kt = 0; kt < 16; ++kt) {
            float fn[8];
            const int kn = (kt + 1) & 15;
            #pragma unroll
            for (int j = 0; j < 8; ++j) fn[j] = Wl[(kn * 16 + j) * 256];
            bf16x8 b;
            #pragma unroll
            for (int j = 0; j < 8; ++j) b[j] = (__bf16)f[j];
            const bf16x8 a = *(const bf16x8*)&s_a[shx(lm, kt * 16 + lh * 8)];
            acc = __builtin_amdgcn_mfma_f32_32x32x16_bf16(b, a, acc, 0, 0, 0);
            #pragma unroll
            for (int j = 0; j < 8; ++j) f[j] = fn[j];
        }
        const int hh = ct >> 1;
        const float* bias = &bq[ct * 32 + 4 * lh];
        const float* bkp  = &bk[ct * 32 + 4 * lh];
        float part = 0.0f;
        #pragma unroll
        for (int g = 0; g < 4; ++g) {
            bf16x4 v;
            #pragma unroll
            for (int q = 0; q < 4; ++q) {
                const float f2 = acc[g * 4 + q] + bias[8 * g + q];
                part += f2 * bkp[8 * g + q];
                v[q] = (__bf16)f2;
            }
            *(bf16x4*)&s_q[(lm << 8) + ((((ct << 2) + g) ^ lm) << 3) + 4 * lh] = v;
        }
        part += __shfl_xor(part, 32, 64);
        if (lane < 32) atomicAdd(&s_qb[lm * 4 + hh], part);
    }
    __syncthreads();

    // ---- qb out ----
    if (t < 128) qbg[(size_t)(b0 + (t >> 2)) * 4 + (t & 3)] = s_qb[t];

    // ---- qk[row][h*64+d] = sum_e Wk[h][d][e]*q[row][h*64+e] via MFMA ----
    {
        const int h = wv >> 1, c2 = wv & 1;
        acc = vzero;
        #pragma unroll
        for (int kt = 0; kt < 4; ++kt) {
            const float* wk = Wk + ((size_t)(h * 64 + c2 * 32 + lm) * 64 + kt * 16 + lh * 8);
            const float4 w0 = *(const float4*)wk;
            const float4 w1 = *(const float4*)(wk + 4);
            bf16x8 b;
            b[0]=(__bf16)w0.x; b[1]=(__bf16)w0.y; b[2]=(__bf16)w0.z; b[3]=(__bf16)w0.w;
            b[4]=(__bf16)w1.x; b[5]=(__bf16)w1.y; b[6]=(__bf16)w1.z; b[7]=(__bf16)w1.w;
            const bf16x8 a = *(const bf16x8*)&s_q[shx(lm, h * 64 + kt * 16 + lh * 8)];
            acc = __builtin_amdgcn_mfma_f32_32x32x16_bf16(b, a, acc, 0, 0, 0);
        }
        float* dstg = &qkg[(size_t)(b0 + lm) * 256 + h * 64 + c2 * 32 + 4 * lh];
        #pragma unroll
        for (int g = 0; g < 4; ++g) {
            float4 fv;
            float* fp = &fv.x;
            #pragma unroll
            for (int q = 0; q < 4; ++q) fp[q] = acc[g * 4 + q];
            *(float4*)&dstg[8 * g] = fv;
        }
    }
}

// ---------------------------------------------------------------------------
// k_obj: R10 structure (M=128, 512 thr, 2 WG/CU, depth-1 B rotation,
// bias-init acc, cross-barrier B prologue prefetch) with a BARRIER-FREE
// attention tail: am/amsum/p flow through __shfl within the owning wave
// (phases B->C->D need no __syncthreads; s_am/s_p/s_amsum deleted).
// ---------------------------------------------------------------------------
__global__ __launch_bounds__(512, 4) void k_obj(
    const float* __restrict__ obs,  const __bf16* __restrict__ wp,
    const float* __restrict__ pb1,  const float* __restrict__ pb2,
    const float* __restrict__ pb3,  const float* __restrict__ qkg,
    const float* __restrict__ qbg,  const float* __restrict__ bv,
    const float* __restrict__ Wv,   float* __restrict__ out)
{
    __shared__ __align__(16) __bf16 s_h[128 * 256];   // 65536 B (swizzled)
    __shared__ __align__(16) __bf16 s_f[128 * 40];    // 10240 B feats
    __shared__ float s_mask[128];
    __shared__ float s_qk[8 * 64];

    const int t  = threadIdx.x;
    const int b0 = blockIdx.x * 2;
    const int wv = t >> 6, lane = t & 63;
    const int lm = lane & 31, lh = lane >> 5;
    const int rtp = wv & 1;
    const int ct0 = (wv >> 1) * 2;
    const int row0 = rtp * 64 + lm;
    const int row1 = row0 + 32;

    // GEMM1 B-fragments: independent of staging, issue early
    bf16x8 b1[2][2];
    {
        const bf16x8* Bg = (const bf16x8*)wp + S_PW1 * 512;
        #pragma unroll
        for (int kt = 0; kt < 2; ++kt)
            #pragma unroll
            for (int c = 0; c < 2; ++c)
                b1[kt][c] = Bg[(kt * 8 + ct0 + c) * 64 + lane];
    }

    // ---- stage feats (128 x 32 bf16, stride 40) + mask ----
    {
        const int row = t >> 2, q4 = t & 3;
        const float* src = obs + (size_t)(b0 + (row >> 6)) * OBS_COLS
                               + (row & 63) * 32 + q4 * 8;
        const float4 v0 = ((const float4*)src)[0];
        const float4 v1 = ((const float4*)src)[1];
        bf16x8 o;
        o[0]=(__bf16)v0.x; o[1]=(__bf16)v0.y; o[2]=(__bf16)v0.z; o[3]=(__bf16)v0.w;
        o[4]=(__bf16)v1.x; o[5]=(__bf16)v1.y; o[6]=(__bf16)v1.z; o[7]=(__bf16)v1.w;
        *(bf16x8*)&s_f[row * 40 + q4 * 8] = o;
        if (q4 == 3) s_mask[row] = v1.w;
    }
    // stage qk for both batch rows (coalesced float4)
    if (t < 128) ((float4*)s_qk)[t] = ((const float4*)(qkg + (size_t)b0 * 256))[t];
    __syncthreads();

    f32x16 acc[2][2];

    // ========== GEMM1: h1 = relu(feats @ W1p + b1), K=32 ==========
    {
        #pragma unroll
        for (int c = 0; c < 2; ++c) {
            #pragma unroll
            for (int g = 0; g < 4; ++g) {
                const float4 bv4 = *(const float4*)&pb1[(ct0 + c) * 32 + 4 * lh + 8 * g];
                acc[0][c][g*4+0] = bv4.x; acc[0][c][g*4+1] = bv4.y;
                acc[0][c][g*4+2] = bv4.z; acc[0][c][g*4+3] = bv4.w;
            }
            acc[1][c] = acc[0][c];
        }
        #pragma unroll
        for (int kt = 0; kt < 2; ++kt) {
            const bf16x8 a0 = *(const bf16x8*)&s_f[row0 * 40 + kt * 16 + lh * 8];
            const bf16x8 a1 = *(const bf16x8*)&s_f[row1 * 40 + kt * 16 + lh * 8];
            acc[0][0] = __builtin_amdgcn_mfma_f32_32x32x16_bf16(b1[kt][0], a0, acc[0][0], 0, 0, 0);
            acc[0][1] = __builtin_amdgcn_mfma_f32_32x32x16_bf16(b1[kt][1], a0, acc[0][1], 0, 0, 0);
            acc[1][0] = __builtin_amdgcn_mfma_f32_32x32x16_bf16(b1[kt][0], a1, acc[1][0], 0, 0, 0);
            acc[1][1] = __builtin_amdgcn_mfma_f32_32x32x16_bf16(b1[kt][1], a1, acc[1][1], 0, 0, 0);
        }
        #pragma unroll
        for (int r = 0; r < 2; ++r) {
            const int row = r ? row1 : row0;
            #pragma unroll
            for (int c = 0; c < 2; ++c) {
                #pragma unroll
                for (int g = 0; g < 4; ++g) {
                    bf16x4 v;
                    #pragma unroll
                    for (int q = 0; q < 4; ++q)
                        v[q] = (__bf16)fmaxf(acc[r][c][g * 4 + q], 0.0f);
                    *(bf16x4*)&s_h[(row << 8) + (((((ct0 + c) << 2) + g) ^ lm) << 3) + 4 * lh] = v;
                }
            }
        }
    }
    // prefetch GEMM2's first B-pair across the barrier
    const bf16x8* Bg2 = (const bf16x8*)wp + S_PW2 * 512;
    bf16x8 p20 = Bg2[(ct0 + 0) * 64 + lane];
    bf16x8 p21 = Bg2[(ct0 + 1) * 64 + lane];
    __syncthreads();

    // ========== GEMM2: h2 = relu(h1 @ W2 + b2), K=256, depth-1 rot ==========
    {
        #pragma unroll
        for (int c = 0; c < 2; ++c) {
            #pragma unroll
            for (int g = 0; g < 4; ++g) {
                const float4 bv4 = *(const float4*)&pb2[(ct0 + c) * 32 + 4 * lh + 8 * g];
                acc[0][c][g*4+0] = bv4.x; acc[0][c][g*4+1] = bv4.y;
                acc[0][c][g*4+2] = bv4.z; acc[0][c][g*4+3] = bv4.w;
            }
            acc[1][c] = acc[0][c];
        }
        bf16x8 bc0 = p20, bc1 = p21;
        #pragma unroll 4
        for (int kt = 0; kt < 16; ++kt) {
            const int kn = (kt + 1) & 15;
            const bf16x8 bn0 = Bg2[(kn * 8 + ct0 + 0) * 64 + lane];
            const bf16x8 bn1 = Bg2[(kn * 8 + ct0 + 1) * 64 + lane];
            const bf16x8 a0 = *(const bf16x8*)&s_h[(row0 << 8) + (((2 * kt + lh) ^ lm) << 3)];
            const bf16x8 a1 = *(const bf16x8*)&s_h[(row1 << 8) + (((2 * kt + lh) ^ lm) << 3)];
            acc[0][0] = __builtin_amdgcn_mfma_f32_32x32x16_bf16(bc0, a0, acc[0][0], 0, 0, 0);
            acc[0][1] = __builtin_amdgcn_mfma_f32_32x32x16_bf16(bc1, a0, acc[0][1], 0, 0, 0);
            acc[1][0] = __builtin_amdgcn_mfma_f32_32x32x16_bf16(bc0, a1, acc[1][0], 0, 0, 0);
            acc[1][1] = __builtin_amdgcn_mfma_f32_32x32x16_bf16(bc1, a1, acc[1][1], 0, 0, 0);
            bc0 = bn0; bc1 = bn1;
        }
        __syncthreads();   // all reads of h1 done before in-place overwrite
        #pragma unroll
        for (int r = 0; r < 2; ++r) {
            const int row = r ? row1 : row0;
            #pragma unroll
            for (int c = 0; c < 2; ++c) {
                #pragma unroll
                for (int g = 0; g < 4; ++g) {
                    bf16x4 v;
                    #pragma unroll
                    for (int q = 0; q < 4; ++q)
                        v[q] = (__bf16)fmaxf(acc[r][c][g * 4 + q], 0.0f);
                    *(bf16x4*)&s_h[(row << 8) + (((((ct0 + c) << 2) + g) ^ lm) << 3) + 4 * lh] = v;
                }
            }
        }
    }
    // prefetch GEMM3's first B-pair across the barrier
    const bf16x8* Bg3 = (const bf16x8*)wp + S_PW3 * 512;
    bf16x8 p30 = Bg3[(ct0 + 0) * 64 + lane];
    bf16x8 p31 = Bg3[(ct0 + 1) * 64 + lane];
    __syncthreads();

    // ========== GEMM3: E = (h2 @ W3 + b3) * mask, K=256, depth-1 rot ==========
    {
        #pragma unroll
        for (int c = 0; c < 2; ++c) {
            #pragma unroll
            for (int g = 0; g < 4; ++g) {
                const float4 bv4 = *(const float4*)&pb3[(ct0 + c) * 32 + 4 * lh + 8 * g];
                acc[0][c][g*4+0] = bv4.x; acc[0][c][g*4+1] = bv4.y;
                acc[0][c][g*4+2] = bv4.z; acc[0][c][g*4+3] = bv4.w;
            }
            acc[1][c] = acc[0][c];
        }
        bf16x8 bc0 = p30, bc1 = p31;
        #pragma unroll 4
        for (int kt = 0; kt < 16; ++kt) {
            const int kn = (kt + 1) & 15;
            const bf16x8 bn0 = Bg3[(kn * 8 + ct0 + 0) * 64 + lane];
            const bf16x8 bn1 = Bg3[(kn * 8 + ct0 + 1) * 64 + lane];
            const bf16x8 a0 = *(const bf16x8*)&s_h[(row0 << 8) + (((2 * kt + lh) ^ lm) << 3)];
            const bf16x8 a1 = *(const bf16x8*)&s_h[(row1 << 8) + (((2 * kt + lh) ^ lm) << 3)];
            acc[0][0] = __builtin_amdgcn_mfma_f32_32x32x16_bf16(bc0, a0, acc[0][0], 0, 0, 0);
            acc[0][1] = __builtin_amdgcn_mfma_f32_32x32x16_bf16(bc1, a0, acc[0][1], 0, 0, 0);
            acc[1][0] = __builtin_amdgcn_mfma_f32_32x32x16_bf16(bc0, a1, acc[1][0], 0, 0, 0);
            acc[1][1] = __builtin_amdgcn_mfma_f32_32x32x16_bf16(bc1, a1, acc[1][1], 0, 0, 0);
            bc0 = bn0; bc1 = bn1;
        }
        __syncthreads();
        #pragma unroll
        for (int r = 0; r < 2; ++r) {
            const int row = r ? row1 : row0;
            const float mk = s_mask[row];
            #pragma unroll
            for (int c = 0; c < 2; ++c) {
                #pragma unroll
                for (int g = 0; g < 4; ++g) {
                    bf16x4 v;
                    #pragma unroll
                    for (int q = 0; q < 4; ++q)
                        v[q] = (__bf16)(acc[r][c][g * 4 + q] * mk);
                    *(bf16x4*)&s_h[(row << 8) + (((((ct0 + c) << 2) + g) ^ lm) << 3) + 4 * lh] = v;
                }
            }
        }
    }
    __syncthreads();   // E complete; attention tail below is barrier-free

    // ---- Phase B: logits + softmax; am stays in-register (lane = object) ----
    const int r_ = wv >> 2, h_ = wv & 3;
    float am, amsum;
    {
        const float qb = qbg[(size_t)(b0 + r_) * 4 + h_];
        const int erow = r_ * 64 + lane;
        float dot = 0.0f;
        #pragma unroll
        for (int d8 = 0; d8 < 8; ++d8) {
            const bf16x8 ev = *(const bf16x8*)&s_h[(erow << 8) + ((((h_ << 3) + d8) ^ (erow & 31)) << 3)];
            const float* kv = &s_qk[(r_ * 4 + h_) * 64 + d8 * 8];
            #pragma unroll
            for (int j = 0; j < 8; ++j) dot += (float)ev[j] * kv[j];
        }
        const float mk = s_mask[erow];
        float logit = (dot + qb) * 0.0625f;
        if (mk == 0.0f) logit = -1.0e9f;
        float m = logit;
        #pragma unroll
        for (int off = 32; off > 0; off >>= 1) m = fmaxf(m, __shfl_xor(m, off, 64));
        const float ex = __expf(logit - m);
        float ssum = ex;
        #pragma unroll
        for (int off = 32; off > 0; off >>= 1) ssum += __shfl_xor(ssum, off, 64);
        am = (ex / ssum) * mk;
        amsum = am;
        #pragma unroll
        for (int off = 32; off > 0; off >>= 1) amsum += __shfl_xor(amsum, off, 64);
    }

    // ---- Phase C: p[d] = sum_n am[n]*E[n][h*64+d]; am via shfl, p -> lane d ----
    float pval;
    {
        const int dblk = lane >> 3, j = lane & 7;
        const int blk = (h_ << 3) + dblk;
        float a[8];
        #pragma unroll
        for (int dd = 0; dd < 8; ++dd) a[dd] = 0.0f;
        #pragma unroll
        for (int nn = 0; nn < 8; ++nn) {
            const int n = j * 8 + nn;
            const int row = r_ * 64 + n;
            const bf16x8 ev = *(const bf16x8*)&s_h[(row << 8) + ((blk ^ (row & 31)) << 3)];
            const float amv = __shfl(am, n, 64);
            #pragma unroll
            for (int dd = 0; dd < 8; ++dd) a[dd] += amv * (float)ev[dd];
        }
        #pragma unroll
        for (int off = 1; off <= 4; off <<= 1)
            #pragma unroll
            for (int dd = 0; dd < 8; ++dd) a[dd] += __shfl_xor(a[dd], off, 64);
        const float s01 = (j & 1) ? a[1] : a[0];
        const float s23 = (j & 1) ? a[3] : a[2];
        const float s45 = (j & 1) ? a[5] : a[4];
        const float s67 = (j & 1) ? a[7] : a[6];
        const float t03 = (j & 2) ? s23 : s01;
        const float t47 = (j & 2) ? s67 : s45;
        pval = (j & 4) ? t47 : t03;      // lane holds p[lane]
    }

    // ---- Phase D: out_emb = p @ Wv + amsum*bv; p via shfl ----
    {
        const int eblk = lane >> 3, j = lane & 7;
        float a[8];
        #pragma unroll
        for (int ee = 0; ee < 8; ++ee) a[ee] = 0.0f;
        const float* wvb = Wv + (size_t)h_ * 4096 + eblk * 8;
        #pragma unroll
        for (int dd = 0; dd < 8; ++dd) {
            const int d = j * 8 + dd;
            const float pd = __shfl(pval, d, 64);
            const float4 w0 = *(const float4*)&wvb[d * 64];
            const float4 w1 = *(const float4*)&wvb[d * 64 + 4];
            a[0] += pd * w0.x; a[1] += pd * w0.y;
            a[2] += pd * w0.z; a[3] += pd * w0.w;
            a[4] += pd * w1.x; a[5] += pd * w1.y;
            a[6] += pd * w1.z; a[7] += pd * w1.w;
        }
        #pragma unroll
        for (int off = 1; off <= 4; off <<= 1)
            #pragma unroll
            for (int ee = 0; ee < 8; ++ee) a[ee] += __shfl_xor(a[ee], off, 64);
        const float s01 = (j & 1) ? a[1] : a[0];
        const float s23 = (j & 1) ? a[3] : a[2];
        const float s45 = (j & 1) ? a[5] : a[4];
        const float s67 = (j & 1) ? a[7] : a[6];
        const float t03 = (j & 2) ? s23 : s01;
        const float t47 = (j & 2) ? s67 : s45;
        float val = (j & 4) ? t47 : t03;
        val += amsum * bv[h_ * 64 + lane];   // e == lane; amsum lane-uniform
        out[(size_t)(b0 + r_) * OUTC + EMB + h_ * 64 + lane] = val;
    }
}

extern "C" void kernel_launch(void* const* d_in, const int* in_sizes, int n_in,
                              void* d_out, int out_size, void* d_ws, size_t ws_size,
                              hipStream_t stream)
{
    const float* obs = (const float*)d_in[0];
    const float* oW1 = (const float*)d_in[1];
    const float* ob1 = (const float*)d_in[2];
    const float* oW2 = (const float*)d_in[3];
    const float* ob2 = (const float*)d_in[4];
    const float* pW1 = (const float*)d_in[5];
    const float* pb1 = (const float*)d_in[6];
    const float* pW2 = (const float*)d_in[7];
    const float* pb2 = (const float*)d_in[8];
    const float* pW3 = (const float*)d_in[9];
    const float* pb3 = (const float*)d_in[10];
    const float* Wq  = (const float*)d_in[11];
    const float* bq  = (const float*)d_in[12];
    const float* Wk  = (const float*)d_in[13];
    const float* bk  = (const float*)d_in[14];
    const float* Wv  = (const float*)d_in[15];
    const float* bv  = (const float*)d_in[16];
    float*  out = (float*)d_out;
    float*  qkg = (float*)d_ws;
    float*  qbg = (float*)((char*)d_ws + QK_BYTES);
    __bf16* wp  = (__bf16*)((char*)d_ws + QK_BYTES + QB_BYTES);

    k_oth<<<BATCH / 32, 512, 0, stream>>>(obs, oW1, ob1, oW2, ob2, Wq, bq,
                                          Wk, bk, pW1, pW2, pW3,
                                          out, qkg, qbg, wp);
    k_obj<<<BATCH / 2, 512, 0, stream>>>(obs, wp, pb1, pb2, pb3, qkg, qbg,
                                         bv, Wv, out);
}